// Round 1
// baseline (758.432 us; speedup 1.0000x reference)
//
#include <hip/hip_runtime.h>
#include <hip/hip_bf16.h>
#include <math.h>

typedef __bf16 bf16x8 __attribute__((ext_vector_type(8)));
typedef float f32x4 __attribute__((ext_vector_type(4)));

#define MFMA16(a,b,c) __builtin_amdgcn_mfma_f32_16x16x32_bf16(a,b,c,0,0,0)

static constexpr int Nn = 48, Ff = 4, Hh = 256;
static constexpr int Ee = 2256, BT = 64;
static constexpr int ETILE = 128, NTILES = 18;         // 18*128 = 2304 >= 2256
static constexpr float BN_RS = 0.9999950000374998f;     // 1/sqrt(1+1e-5)

// ---- ws layout (bytes) ----
// wf (bf16 frags, 4 matrices: mf2_0, mf2_1, at1_w1, at1_w2): 0 .. 524288
// node transposed weights (fp32): 524288 .. 1597568
// g_agg [64][48][256] fp32: 1605632 .. 4751360
static constexpr size_t WS_WF = 0;
static constexpr size_t WS_TN = 524288;
static constexpr size_t WS_AGG = 1605632;

// LDS layout for edge kernel (bytes)
static constexpr int LDS_ACTA = 0;          // [128][256] bf16 (swizzled) = 65536
static constexpr int LDS_ACTB = 65536;      // [128][256] bf16 (swizzled) = 65536
static constexpr int LDS_WSG  = 131072;     // 16384 staging (weight chunk / mf1_w)
static constexpr int LDS_XS   = 147456;     // 192 f32
static constexpr int LDS_PM   = 148224;     // [128][8] f32
static constexpr int LDS_RT   = 152320;     // [128][2] f32
static constexpr int LDS_BIAS = 153344;     // 256 f32
static constexpr int LDS_SC   = 154368;     // 256 f32
static constexpr int LDS_SBE  = 155392;     // 256 f32
static constexpr int LDS_EDGE_BYTES = 156416;

__device__ __forceinline__ float eluf(float v) { return v > 0.f ? v : expm1f(v); }

// row-swizzled byte offset inside a [128][512B] activation buffer
__device__ __forceinline__ int aoff(int e, int colbyte) {
  return e * 512 + (colbyte ^ ((e & 7) << 4));
}

// Staged K=256 GEMM: 128 edges x 256 out, A from swizzled LDS act buffer,
// B (weights) pre-arranged fragment-linear in global, staged per-32-K chunk.
__device__ __forceinline__ void gemm256(const char* inbase, const __bf16* wfmat,
                                        const float* bsrc, char* wsg, float* bias,
                                        int tid, int lane, int arow, int kgrp,
                                        f32x4 acc[16],
                                        const float* sc_src, const float* be_src,
                                        float* sc, float* sbe) {
#pragma unroll
  for (int nt = 0; nt < 16; ++nt) acc[nt] = (f32x4){0.f, 0.f, 0.f, 0.f};
  const uint4* wsrc = (const uint4*)wfmat;
  uint4 r0 = wsrc[tid], r1 = wsrc[tid + 512];
  for (int kt = 0; kt < 8; ++kt) {
    __syncthreads();  // previous wsg readers done
    ((uint4*)wsg)[tid] = r0;
    ((uint4*)wsg)[tid + 512] = r1;
    if (kt < 7) { r0 = wsrc[(kt + 1) * 1024 + tid]; r1 = wsrc[(kt + 1) * 1024 + 512 + tid]; }
    if (kt == 0) {
      if (tid < Hh) bias[tid] = bsrc[tid];
      if (sc_src != nullptr && tid < Hh) {
        sc[tid] = sc_src[tid] * BN_RS;
        sbe[tid] = be_src[tid];
      }
    }
    __syncthreads();  // chunk staged
    bf16x8 af = *(const bf16x8*)(inbase + arow * 512 + ((kt * 64 + kgrp * 16) ^ ((arow & 7) << 4)));
#pragma unroll
    for (int nt = 0; nt < 16; ++nt) {
      bf16x8 bfr = *(const bf16x8*)(wsg + (nt * 64 + lane) * 16);
      acc[nt] = MFMA16(af, bfr, acc[nt]);
    }
  }
}

__global__ __launch_bounds__(512, 2)
void edge_kernel(const float* __restrict__ x, const float* __restrict__ rel_rec,
                 const float* __restrict__ rel_send, const float* __restrict__ rel_type,
                 const float* __restrict__ mf1_w, const float* __restrict__ mf1_b,
                 const float* __restrict__ mf2_b, const float* __restrict__ at1_b1,
                 const float* __restrict__ at1_b2, const float* __restrict__ at1_g,
                 const float* __restrict__ at1_be, const __bf16* __restrict__ wf,
                 float* __restrict__ g_agg) {
  extern __shared__ char smem[];
  char* wsg = smem + LDS_WSG;
  float* xs = (float*)(smem + LDS_XS);
  float* pm = (float*)(smem + LDS_PM);
  float* rt = (float*)(smem + LDS_RT);
  float* bias = (float*)(smem + LDS_BIAS);
  float* sc = (float*)(smem + LDS_SC);
  float* sbe = (float*)(smem + LDS_SBE);

  const int tid = threadIdx.x;
  const int lane = tid & 63;
  const int wv = tid >> 6;
  const int m0 = wv * 16;
  const int slice = blockIdx.x / NTILES;
  const int tile = blockIdx.x % NTILES;
  const int e0 = tile * ETILE;
  const int ne = min(ETILE, Ee - e0);
  const int arow = m0 + (lane & 15);
  const int kgrp = lane >> 4;

  if (tid < Nn * Ff) xs[tid] = x[slice * Nn * Ff + tid];
  if (tid < ETILE * 2) {
    int e = tid >> 1, i = tid & 1;
    rt[tid] = (e < ne) ? rel_type[(size_t)slice * Ee * 2 + (size_t)(e0 + e) * 2 + i] : 0.f;
  }
  __syncthreads();

  // pre_msg = [senders(F), receivers(F)]
  for (int t = tid; t < ETILE * 8; t += 512) {
    int e = t >> 3, c = t & 7;
    float s = 0.f;
    if (e < ne) {
      const float* rel = ((c < 4) ? rel_send : rel_rec) + (size_t)(e0 + e) * Nn;
      int f = c & 3;
#pragma unroll
      for (int n = 0; n < Nn; ++n) s += rel[n] * xs[n * 4 + f];
    }
    pm[t] = s;
  }

  f32x4 allm[16];
#pragma unroll
  for (int nt = 0; nt < 16; ++nt) allm[nt] = (f32x4){0.f, 0.f, 0.f, 0.f};

  for (int ty = 0; ty < 2; ++ty) {
    // stage mf1_w[ty] (2048 f32) into wsg + mf1_b into bias
    __syncthreads();
    ((uint4*)wsg)[tid] = ((const uint4*)(mf1_w + ty * Hh * 8))[tid];
    if (tid < Hh) bias[tid] = mf1_b[ty * Hh + tid];
    __syncthreads();
    // fc1 (K=8) scalar -> actA (bf16, swizzled A-frag friendly rows)
    const float* wsf = (const float*)wsg;
    for (int t = tid; t < ETILE * 32; t += 512) {
      int e = t & (ETILE - 1), hc = t >> 7;
      float pmr[8];
#pragma unroll
      for (int k = 0; k < 8; ++k) pmr[k] = pm[e * 8 + k];
      bf16x8 pv;
#pragma unroll
      for (int j = 0; j < 8; ++j) {
        int h = hc * 8 + j;
        float s = bias[h];
#pragma unroll
        for (int k = 0; k < 8; ++k) s = fmaf(pmr[k], wsf[h * 8 + k], s);
        pv[j] = (__bf16)fmaxf(s, 0.f);
      }
      *(bf16x8*)(smem + LDS_ACTA + aoff(e, hc * 16)) = pv;
    }
    // mf2[ty]: [128,256] @ [256,256]
    f32x4 acc[16];
    gemm256(smem + LDS_ACTA, wf + (size_t)ty * 65536, mf2_b + ty * Hh, wsg, bias,
            tid, lane, arow, kgrp, acc, nullptr, nullptr, nullptr, nullptr);
    float rtv[4];
#pragma unroll
    for (int r = 0; r < 4; ++r) rtv[r] = rt[(m0 + kgrp * 4 + r) * 2 + ty];
#pragma unroll
    for (int nt = 0; nt < 16; ++nt) {
      float bb = bias[nt * 16 + (lane & 15)];
#pragma unroll
      for (int r = 0; r < 4; ++r)
        allm[nt][r] += fmaxf(acc[nt][r] + bb, 0.f) * rtv[r];
    }
  }

  // all_msgs -> actB (bf16), rows are wave-private so no extra barrier needed here
#pragma unroll
  for (int nt = 0; nt < 16; ++nt)
#pragma unroll
    for (int r = 0; r < 4; ++r) {
      int e = m0 + kgrp * 4 + r;
      int cb = (nt * 16 + (lane & 15)) * 2;
      *(__bf16*)(smem + LDS_ACTB + aoff(e, cb)) = (__bf16)allm[nt][r];
    }

  // at1 layer 1: actB -> elu -> actA
  {
    f32x4 acc[16];
    gemm256(smem + LDS_ACTB, wf + (size_t)2 * 65536, at1_b1, wsg, bias,
            tid, lane, arow, kgrp, acc, nullptr, nullptr, nullptr, nullptr);
#pragma unroll
    for (int nt = 0; nt < 16; ++nt) {
      float bb = bias[nt * 16 + (lane & 15)];
#pragma unroll
      for (int r = 0; r < 4; ++r) {
        int e = m0 + kgrp * 4 + r;
        int cb = (nt * 16 + (lane & 15)) * 2;
        *(__bf16*)(smem + LDS_ACTA + aoff(e, cb)) = (__bf16)eluf(acc[nt][r] + bb);
      }
    }
  }
  // at1 layer 2: actA -> elu -> *scale + be -> actB (= h_edges)
  {
    f32x4 acc[16];
    gemm256(smem + LDS_ACTA, wf + (size_t)3 * 65536, at1_b2, wsg, bias,
            tid, lane, arow, kgrp, acc, at1_g, at1_be, sc, sbe);
#pragma unroll
    for (int nt = 0; nt < 16; ++nt) {
      int col = nt * 16 + (lane & 15);
      float bb = bias[col], s1 = sc[col], s2 = sbe[col];
#pragma unroll
      for (int r = 0; r < 4; ++r) {
        int e = m0 + kgrp * 4 + r;
        float v = eluf(acc[nt][r] + bb) * s1 + s2;
        *(__bf16*)(smem + LDS_ACTB + aoff(e, col * 2)) = (__bf16)v;
      }
    }
  }

  // aggregation: agg[n][h] += sum_e rel_rec[e][n] * h[e][h]
  __syncthreads();  // all h writes done; actA free for rel_rec tile
  float* rrs = (float*)(smem + LDS_ACTA);
  for (int t = tid; t < ETILE * Nn; t += 512) {
    int e = t / Nn, n = t - e * Nn;
    rrs[t] = (e < ne) ? rel_rec[(size_t)(e0 + e) * Nn + n] : 0.f;
  }
  __syncthreads();
#pragma unroll
  for (int p = 0; p < 3; ++p) {
    int t = p * 512 + tid;  // t < 1536 = 48*32
    int n = t >> 5, hc = t & 31;
    float a8[8] = {0.f, 0.f, 0.f, 0.f, 0.f, 0.f, 0.f, 0.f};
    for (int e = 0; e < ETILE; ++e) {
      bf16x8 hv = *(const bf16x8*)(smem + LDS_ACTB + aoff(e, hc * 16));
      float wvv = rrs[e * Nn + n];
#pragma unroll
      for (int j = 0; j < 8; ++j) a8[j] += wvv * (float)hv[j];
    }
    float* dst = g_agg + (size_t)slice * Nn * Hh + n * Hh + hc * 8;
#pragma unroll
    for (int j = 0; j < 8; ++j) atomicAdd(dst + j, a8[j]);
  }
}

// convert 4 weight matrices [256][256] fp32 -> bf16 MFMA-B fragment-linear layout
__global__ void prep_frag(const float* __restrict__ mf2_w, const float* __restrict__ at1_w1,
                          const float* __restrict__ at1_w2, __bf16* __restrict__ wfdst) {
  int id = blockIdx.x * 256 + threadIdx.x;  // 32768 total
  int mat = id >> 13, r = id & 8191;
  int kt = r >> 10, q = r & 1023, nt = q >> 6, l = q & 63;
  int row = nt * 16 + (l & 15), col = kt * 32 + (l >> 4) * 8;
  const float* src = (mat == 0) ? mf2_w : (mat == 1) ? (mf2_w + 65536)
                   : (mat == 2) ? at1_w1 : at1_w2;
  const float* p = src + row * 256 + col;
  __bf16* d = wfdst + (size_t)mat * 65536 + ((size_t)(kt * 16 + nt) * 64 + l) * 8;
#pragma unroll
  for (int j = 0; j < 8; ++j) d[j] = (__bf16)p[j];
}

// transpose node-side weights (fp32) so lane reads WT[k*O+o] are coalesced
__global__ void prep_node(const float* __restrict__ at5_w1, const float* __restrict__ at5_w2,
                          const float* __restrict__ o1_w, const float* __restrict__ o2_w,
                          const float* __restrict__ o3_w, float* __restrict__ ws) {
  int id = blockIdx.x * 256 + threadIdx.x;
  float* T1 = ws;
  float* T2 = T1 + 67600;
  float* To1 = T2 + 67600;
  float* To2 = To1 + 66560;
  float* To3 = To2 + 65536;
  if (id < 67600) { int o = id % 260, k = id / 260; T1[k * 260 + o] = at5_w1[o * 260 + k]; return; }
  id -= 67600;
  if (id < 67600) { int o = id % 260, k = id / 260; T2[k * 260 + o] = at5_w2[o * 260 + k]; return; }
  id -= 67600;
  if (id < 66560) { int o = id & 255, k = id >> 8; To1[k * 256 + o] = o1_w[o * 260 + k]; return; }
  id -= 66560;
  if (id < 65536) { int o = id & 255, k = id >> 8; To2[k * 256 + o] = o2_w[o * 256 + k]; return; }
  id -= 65536;
  if (id < 1024) { int f = id & 3, k = id >> 2; To3[k * 4 + f] = o3_w[f * 256 + k]; }
}

__global__ __launch_bounds__(256, 4)
void node_kernel(const float* __restrict__ g_agg, const float* __restrict__ x,
                 const float* __restrict__ T1, const float* __restrict__ T2,
                 const float* __restrict__ To1, const float* __restrict__ To2,
                 const float* __restrict__ To3, const float* __restrict__ at5_b1,
                 const float* __restrict__ at5_b2, const float* __restrict__ at5_g,
                 const float* __restrict__ at5_be, const float* __restrict__ o1_b,
                 const float* __restrict__ o2_b, const float* __restrict__ o3_b,
                 float* __restrict__ out) {
  __shared__ float bufA[12 * 264], bufB[12 * 264], xres[12 * 4];
  const int tid = threadIdx.x;
  const int slice = blockIdx.x >> 2, rg = blockIdx.x & 3;
  const int n0 = rg * 12;
  for (int t = tid; t < 12 * 256; t += 256) {
    int r = t >> 8, h = t & 255;
    bufA[r * 264 + h] = g_agg[(size_t)slice * 12288 + (size_t)(n0 + r) * 256 + h];
  }
  if (tid < 48) {
    int r = tid >> 2, f = tid & 3;
    float v = x[(size_t)slice * 192 + (n0 + r) * 4 + f];
    bufA[r * 264 + 256 + f] = v;
    xres[tid] = v;
  }
  __syncthreads();

  auto layer = [&](const float* WT, const float* bsrc, const float* in, float* outb,
                   int K, int O, int act, const float* gsc, const float* gbe) {
    for (int o = tid; o < O; o += 256) {
      float a[12];
      float bb = bsrc[o];
#pragma unroll
      for (int r = 0; r < 12; ++r) a[r] = bb;
      for (int k = 0; k < K; ++k) {
        float w = WT[k * O + o];
#pragma unroll
        for (int r = 0; r < 12; ++r) a[r] = fmaf(in[r * 264 + k], w, a[r]);
      }
      float scv = 1.f, bev = 0.f;
      if (act == 2) { scv = gsc[o] * BN_RS; bev = gbe[o]; }
#pragma unroll
      for (int r = 0; r < 12; ++r) {
        float v = a[r];
        v = (act == 0) ? fmaxf(v, 0.f) : eluf(v);
        if (act == 2) v = v * scv + bev;
        outb[r * 264 + o] = v;
      }
    }
    __syncthreads();
  };

  layer(T1, at5_b1, bufA, bufB, 260, 260, 1, nullptr, nullptr);
  layer(T2, at5_b2, bufB, bufA, 260, 260, 2, at5_g, at5_be);
  layer(To1, o1_b, bufA, bufB, 260, 256, 0, nullptr, nullptr);
  layer(To2, o2_b, bufB, bufA, 256, 256, 0, nullptr, nullptr);
  if (tid < 48) {
    int r = tid >> 2, f = tid & 3;
    float s = o3_b[f];
    for (int k = 0; k < 256; ++k) s = fmaf(bufA[r * 264 + k], To3[k * 4 + f], s);
    out[(size_t)slice * 192 + (n0 + r) * 4 + f] = xres[tid] + s;
  }
}

extern "C" void kernel_launch(void* const* d_in, const int* in_sizes, int n_in,
                              void* d_out, int out_size, void* d_ws, size_t ws_size,
                              hipStream_t stream) {
  const float* x = (const float*)d_in[0];
  const float* rel_rec = (const float*)d_in[1];
  const float* rel_send = (const float*)d_in[2];
  const float* rel_type = (const float*)d_in[3];
  const float* mf1_w = (const float*)d_in[4];
  const float* mf1_b = (const float*)d_in[5];
  const float* mf2_w = (const float*)d_in[6];
  const float* mf2_b = (const float*)d_in[7];
  const float* at1_w1 = (const float*)d_in[8];
  const float* at1_b1 = (const float*)d_in[9];
  const float* at1_w2 = (const float*)d_in[10];
  const float* at1_b2 = (const float*)d_in[11];
  const float* at1_g = (const float*)d_in[12];
  const float* at1_be = (const float*)d_in[13];
  const float* at5_w1 = (const float*)d_in[14];
  const float* at5_b1 = (const float*)d_in[15];
  const float* at5_w2 = (const float*)d_in[16];
  const float* at5_b2 = (const float*)d_in[17];
  const float* at5_g = (const float*)d_in[18];
  const float* at5_be = (const float*)d_in[19];
  const float* o1_w = (const float*)d_in[20];
  const float* o1_b = (const float*)d_in[21];
  const float* o2_w = (const float*)d_in[22];
  const float* o2_b = (const float*)d_in[23];
  const float* o3_w = (const float*)d_in[24];
  const float* o3_b = (const float*)d_in[25];

  char* ws = (char*)d_ws;
  __bf16* wf = (__bf16*)(ws + WS_WF);
  float* tnode = (float*)(ws + WS_TN);
  float* g_agg = (float*)(ws + WS_AGG);

  hipMemsetAsync(g_agg, 0, (size_t)BT * Nn * Hh * 4, stream);
  prep_frag<<<128, 256, 0, stream>>>(mf2_w, at1_w1, at1_w2, wf);
  prep_node<<<1049, 256, 0, stream>>>(at5_w1, at5_w2, o1_w, o2_w, o3_w, tnode);

  hipFuncSetAttribute((const void*)edge_kernel,
                      hipFuncAttributeMaxDynamicSharedMemorySize, LDS_EDGE_BYTES);
  edge_kernel<<<BT * NTILES, 512, LDS_EDGE_BYTES, stream>>>(
      x, rel_rec, rel_send, rel_type, mf1_w, mf1_b, mf2_b, at1_b1, at1_b2,
      at1_g, at1_be, wf, g_agg);

  node_kernel<<<256, 256, 0, stream>>>(g_agg, x, tnode, tnode + 67600,
                                       tnode + 135200, tnode + 201760, tnode + 267296,
                                       at5_b1, at5_b2, at5_g, at5_be,
                                       o1_b, o2_b, o3_b, (float*)d_out);
}

// Round 2
// 627.686 us; speedup vs baseline: 1.2083x; 1.2083x over previous
//
#include <hip/hip_runtime.h>
#include <hip/hip_bf16.h>
#include <math.h>

typedef __bf16 bf16x8 __attribute__((ext_vector_type(8)));
typedef __bf16 bf16x4 __attribute__((ext_vector_type(4)));
typedef float f32x4 __attribute__((ext_vector_type(4)));

#define MFMA16(a,b,c) __builtin_amdgcn_mfma_f32_16x16x32_bf16(a,b,c,0,0,0)

static constexpr int Nn = 48, Hh = 256;
static constexpr int Ee = 2256, BT = 64;
static constexpr int ETILE = 128, NTILES = 18;         // 18*128 = 2304 >= 2256
static constexpr float BN_RS = 0.9999950000374998f;     // 1/sqrt(1+1e-5)

// ---- ws layout (bytes) ----
static constexpr size_t WS_WF  = 0;        // 4 mats bf16 frag-linear: 524288
static constexpr size_t WS_RRA = 524288;   // rel_rec^T A-frags: 18*4*3*64*8 bf16 = 221184
static constexpr size_t WS_TN  = 745472;   // node transposed weights: 268320 f32 = 1073280
static constexpr size_t WS_AGG = 1818752;  // partials [64][18][48][256] f32 = 56623104 (or g_agg 3.1MB fallback)
static constexpr size_t WS_NEED_PART = WS_AGG + (size_t)BT * NTILES * Nn * Hh * 4;

// ---- LDS layout (bytes) ----
static constexpr int LDS_ACT  = 0;        // [128][512B] bf16 act, swizzled; reused as agg B-frags
static constexpr int LDS_WSG  = 65536;    // 2 x 16384 double-buffered weight chunk
static constexpr int LDS_XS   = 98304;    // 192 f32
static constexpr int LDS_PM   = 99072;    // pm[8][128] f32 (k-major, conflict-free)
static constexpr int LDS_RT   = 103168;   // [128][2] f32
static constexpr int LDS_BIAS = 104192;   // 256 f32 (per-GEMM bias)
static constexpr int LDS_FB   = 105216;   // 256 f32 (fc1 bias, separate to avoid race)
static constexpr int LDS_SC   = 106240;   // 256 f32
static constexpr int LDS_SBE  = 107264;   // 256 f32
static constexpr int LDS_EDGE_BYTES = 108288;

__device__ __forceinline__ float eluf(float v) { return v > 0.f ? v : __expf(v) - 1.f; }

// row-swizzled byte offset inside the [128][512B] activation buffer
__device__ __forceinline__ int aoff(int e, int colbyte) {
  return e * 512 + (colbyte ^ ((e & 7) << 4));
}

// K=256 GEMM: 32 edges (2 m-tiles) x 128 cols (8 n-tiles) per wave.
// A from swizzled LDS act (wave-private rows); B frag-linear in global,
// double-buffer staged to LDS, 1 barrier per K-chunk, chunk+2 reg prefetch.
__device__ __forceinline__ void gemm256(char* smem, const __bf16* wfmat,
                                        const float* bsrc, const float* sc_src,
                                        const float* be_src,
                                        int tid, int lane, int m0, int n0b,
                                        f32x4 acc[2][8]) {
  const uint4* wsrc = (const uint4*)wfmat;
  uint4 sa[2], sb[2];
  sa[0] = wsrc[tid];        sb[0] = wsrc[512 + tid];
  sa[1] = wsrc[1024 + tid]; sb[1] = wsrc[1536 + tid];
  uint4* buf0 = (uint4*)(smem + LDS_WSG);
  buf0[tid] = sa[0]; buf0[512 + tid] = sb[0];
  __syncthreads();  // chunk0 staged; all waves past previous phase's LDS reads
  float* bias = (float*)(smem + LDS_BIAS);
  if (tid < Hh) {
    bias[tid] = bsrc[tid];
    if (sc_src != nullptr) {
      ((float*)(smem + LDS_SC))[tid] = sc_src[tid] * BN_RS;
      ((float*)(smem + LDS_SBE))[tid] = be_src[tid];
    }
  }
  const int kgb = (lane >> 4) * 16;  // A k-group byte offset
#pragma unroll
  for (int kt = 0; kt < 8; ++kt) {
    const char* bbase = smem + LDS_WSG + (kt & 1) * 16384;
    const int r0 = m0 + (lane & 15), r1 = r0 + 16;
    bf16x8 af0 = *(const bf16x8*)(smem + LDS_ACT + r0 * 512 + ((kt * 64 + kgb) ^ ((r0 & 7) << 4)));
    bf16x8 af1 = *(const bf16x8*)(smem + LDS_ACT + r1 * 512 + ((kt * 64 + kgb) ^ ((r1 & 7) << 4)));
#pragma unroll
    for (int nt = 0; nt < 8; ++nt) {
      bf16x8 bfr = *(const bf16x8*)(bbase + ((n0b + nt) * 64 + lane) * 16);
      acc[0][nt] = MFMA16(af0, bfr, acc[0][nt]);
      acc[1][nt] = MFMA16(af1, bfr, acc[1][nt]);
    }
    if (kt < 7) {
      uint4* dst = (uint4*)(smem + LDS_WSG + ((kt + 1) & 1) * 16384);
      dst[tid] = sa[(kt + 1) & 1]; dst[512 + tid] = sb[(kt + 1) & 1];
      if (kt < 6) {
        sa[kt & 1] = wsrc[(kt + 2) * 1024 + tid];
        sb[kt & 1] = wsrc[(kt + 2) * 1024 + 512 + tid];
      }
    }
    __syncthreads();
  }
}

template<bool PART>
__global__ __launch_bounds__(512, 2)
void edge_kernel(const float* __restrict__ x, const float* __restrict__ rel_rec,
                 const float* __restrict__ rel_send, const float* __restrict__ rel_type,
                 const float* __restrict__ mf1_w, const float* __restrict__ mf1_b,
                 const float* __restrict__ mf2_b, const float* __restrict__ at1_b1,
                 const float* __restrict__ at1_b2, const float* __restrict__ at1_g,
                 const float* __restrict__ at1_be, const __bf16* __restrict__ wf,
                 const __bf16* __restrict__ rra, float* __restrict__ part) {
  extern __shared__ char smem[];
  float* xs = (float*)(smem + LDS_XS);
  float* pm = (float*)(smem + LDS_PM);
  float* rt = (float*)(smem + LDS_RT);
  float* bias = (float*)(smem + LDS_BIAS);
  float* fb = (float*)(smem + LDS_FB);
  float* sc = (float*)(smem + LDS_SC);
  float* sbe = (float*)(smem + LDS_SBE);

  const int tid = threadIdx.x;
  const int lane = tid & 63;
  const int wv = tid >> 6;
  const int wvM = wv & 3, wvN = wv >> 2;
  const int m0 = wvM * 32, n0 = wvN * 128, n0b = wvN * 8;
  const int slice = blockIdx.x / NTILES;
  const int tile = blockIdx.x % NTILES;
  const int e0 = tile * ETILE;
  const int ne = min(ETILE, Ee - e0);

  if (tid < Nn * 4) xs[tid] = x[slice * Nn * 4 + tid];
  if (tid < ETILE * 2) {
    int e = tid >> 1, i = tid & 1;
    rt[tid] = (e < ne) ? rel_type[((size_t)slice * Ee + e0 + e) * 2 + i] : 0.f;
  }
  __syncthreads();

  // pre_msg k-major: pm[c][e], c: 0-3 senders, 4-7 receivers
#pragma unroll
  for (int p = 0; p < 2; ++p) {
    int t = p * 512 + tid;
    int c = t >> 7, e = t & 127;
    float s = 0.f;
    if (e < ne) {
      const float* rel = ((c < 4) ? rel_send : rel_rec) + (size_t)(e0 + e) * Nn;
      int f = c & 3;
#pragma unroll
      for (int n = 0; n < Nn; ++n) s += rel[n] * xs[n * 4 + f];
    }
    pm[c * 128 + e] = s;
  }

  f32x4 allm[2][8];
#pragma unroll
  for (int mt = 0; mt < 2; ++mt)
#pragma unroll
    for (int nt = 0; nt < 8; ++nt) allm[mt][nt] = (f32x4){0.f, 0.f, 0.f, 0.f};

  for (int ty = 0; ty < 2; ++ty) {
    // stage mf1[ty] into wsg buf1 (disjoint from gemm prologue's buf0) + fc1 bias
    ((uint4*)(smem + LDS_WSG + 16384))[tid] = ((const uint4*)(mf1_w + ty * 2048))[tid];
    if (tid < Hh) fb[tid] = mf1_b[ty * Hh + tid];
    __syncthreads();  // also covers pm writes (ty==0)
    // fc1 (K=8) -> act (bf16, swizzled)
    const float* wsf = (const float*)(smem + LDS_WSG + 16384);
#pragma unroll
    for (int it = 0; it < 8; ++it) {
      int t = it * 512 + tid;
      int e = t & 127, hc = t >> 7;
      float pmr[8];
#pragma unroll
      for (int k = 0; k < 8; ++k) pmr[k] = pm[k * 128 + e];
      bf16x8 pv;
#pragma unroll
      for (int j = 0; j < 8; ++j) {
        int h = hc * 8 + j;
        float s = fb[h];
#pragma unroll
        for (int k = 0; k < 8; ++k) s = fmaf(pmr[k], wsf[h * 8 + k], s);
        pv[j] = (__bf16)fmaxf(s, 0.f);
      }
      *(bf16x8*)(smem + LDS_ACT + aoff(e, hc * 16)) = pv;
    }
    f32x4 acc[2][8];
#pragma unroll
    for (int mt = 0; mt < 2; ++mt)
#pragma unroll
      for (int nt = 0; nt < 8; ++nt) acc[mt][nt] = (f32x4){0.f, 0.f, 0.f, 0.f};
    gemm256(smem, wf + (size_t)ty * 65536, mf2_b + ty * Hh, nullptr, nullptr,
            tid, lane, m0, n0b, acc);
#pragma unroll
    for (int mt = 0; mt < 2; ++mt) {
      float rtv[4];
#pragma unroll
      for (int r = 0; r < 4; ++r) rtv[r] = rt[(m0 + mt * 16 + (lane >> 4) * 4 + r) * 2 + ty];
#pragma unroll
      for (int nt = 0; nt < 8; ++nt) {
        float bb = bias[n0 + nt * 16 + (lane & 15)];
#pragma unroll
        for (int r = 0; r < 4; ++r)
          allm[mt][nt][r] += fmaxf(acc[mt][nt][r] + bb, 0.f) * rtv[r];
      }
    }
  }

  // all_msgs -> act in place (each wave writes its own rows x its own cols)
#pragma unroll
  for (int mt = 0; mt < 2; ++mt)
#pragma unroll
    for (int nt = 0; nt < 8; ++nt)
#pragma unroll
      for (int r = 0; r < 4; ++r) {
        int e = m0 + mt * 16 + (lane >> 4) * 4 + r;
        int cb = (n0 + nt * 16 + (lane & 15)) * 2;
        *(__bf16*)(smem + LDS_ACT + aoff(e, cb)) = (__bf16)allm[mt][nt][r];
      }

  // at1 layer 1: act -> elu -> act (in place)
  {
    f32x4 acc[2][8];
#pragma unroll
    for (int mt = 0; mt < 2; ++mt)
#pragma unroll
      for (int nt = 0; nt < 8; ++nt) acc[mt][nt] = (f32x4){0.f, 0.f, 0.f, 0.f};
    gemm256(smem, wf + (size_t)2 * 65536, at1_b1, nullptr, nullptr,
            tid, lane, m0, n0b, acc);
#pragma unroll
    for (int mt = 0; mt < 2; ++mt)
#pragma unroll
      for (int nt = 0; nt < 8; ++nt) {
        float bb = bias[n0 + nt * 16 + (lane & 15)];
#pragma unroll
        for (int r = 0; r < 4; ++r) {
          int e = m0 + mt * 16 + (lane >> 4) * 4 + r;
          int cb = (n0 + nt * 16 + (lane & 15)) * 2;
          *(__bf16*)(smem + LDS_ACT + aoff(e, cb)) = (__bf16)eluf(acc[mt][nt][r] + bb);
        }
      }
  }

  // at1 layer 2: act -> elu*sc+be -> agg B-frags (overwrites act region)
  {
    f32x4 acc[2][8];
#pragma unroll
    for (int mt = 0; mt < 2; ++mt)
#pragma unroll
      for (int nt = 0; nt < 8; ++nt) acc[mt][nt] = (f32x4){0.f, 0.f, 0.f, 0.f};
    gemm256(smem, wf + (size_t)3 * 65536, at1_b2, at1_g, at1_be,
            tid, lane, m0, n0b, acc);
    // after final kt sync all act reads are done -> safe to overwrite with B-frags
    const int j0 = ((lane >> 4) & 1) * 4;
    const int lh_base = (lane >> 4) >> 1;
#pragma unroll
    for (int mt = 0; mt < 2; ++mt) {
      const int lane_hi = mt * 2 + lh_base;
#pragma unroll
      for (int nt = 0; nt < 8; ++nt) {
        int col = n0 + nt * 16 + (lane & 15);
        float bb = bias[col], s1 = sc[col], s2 = sbe[col];
        bf16x4 pk;
#pragma unroll
        for (int r = 0; r < 4; ++r)
          pk[r] = (__bf16)(eluf(acc[mt][nt][r] + bb) * s1 + s2);
        int addr = ((((wvM * 16) + (n0b + nt)) * 64 + lane_hi * 16 + (lane & 15)) * 8 + j0) * 2;
        *(bf16x4*)(smem + LDS_ACT + addr) = pk;
      }
    }
  }
  __syncthreads();  // B-frags visible

  // aggregation GEMM: agg[n][h] = rel_rec^T @ h_edges  (M=48, N=256, K=128)
  f32x4 ag[3][2];
#pragma unroll
  for (int mt2 = 0; mt2 < 3; ++mt2)
#pragma unroll
    for (int ntl = 0; ntl < 2; ++ntl) ag[mt2][ntl] = (f32x4){0.f, 0.f, 0.f, 0.f};
  const bf16x8* rraw = (const bf16x8*)rra + (size_t)tile * 768;
#pragma unroll
  for (int kt2 = 0; kt2 < 4; ++kt2) {
    bf16x8 b0 = *(const bf16x8*)(smem + LDS_ACT + ((kt2 * 16 + wv * 2 + 0) * 64 + lane) * 16);
    bf16x8 b1 = *(const bf16x8*)(smem + LDS_ACT + ((kt2 * 16 + wv * 2 + 1) * 64 + lane) * 16);
#pragma unroll
    for (int mt2 = 0; mt2 < 3; ++mt2) {
      bf16x8 a = rraw[(kt2 * 3 + mt2) * 64 + lane];
      ag[mt2][0] = MFMA16(a, b0, ag[mt2][0]);
      ag[mt2][1] = MFMA16(a, b1, ag[mt2][1]);
    }
  }
  float* dst = part + ((size_t)(PART ? (slice * NTILES + tile) : slice)) * Nn * Hh;
#pragma unroll
  for (int mt2 = 0; mt2 < 3; ++mt2)
#pragma unroll
    for (int ntl = 0; ntl < 2; ++ntl) {
      int h = (wv * 2 + ntl) * 16 + (lane & 15);
#pragma unroll
      for (int r = 0; r < 4; ++r) {
        int n = mt2 * 16 + (lane >> 4) * 4 + r;
        if (PART) dst[n * Hh + h] = ag[mt2][ntl][r];
        else atomicAdd(dst + n * Hh + h, ag[mt2][ntl][r]);
      }
    }
}

// 4 weight matrices [256][256] fp32 -> bf16 MFMA B-fragment-linear
__global__ void prep_frag(const float* __restrict__ mf2_w, const float* __restrict__ at1_w1,
                          const float* __restrict__ at1_w2, __bf16* __restrict__ wfdst) {
  int id = blockIdx.x * 256 + threadIdx.x;  // 32768 total
  int mat = id >> 13, r = id & 8191;
  int kt = r >> 10, q = r & 1023, nt = q >> 6, l = q & 63;
  int row = nt * 16 + (l & 15), col = kt * 32 + (l >> 4) * 8;
  const float* src = (mat == 0) ? mf2_w : (mat == 1) ? (mf2_w + 65536)
                   : (mat == 2) ? at1_w1 : at1_w2;
  const float* p = src + row * 256 + col;
  __bf16* d = wfdst + (size_t)mat * 65536 + ((size_t)(kt * 16 + nt) * 64 + l) * 8;
#pragma unroll
  for (int j = 0; j < 8; ++j) d[j] = (__bf16)p[j];
}

// rel_rec^T per-tile bf16 A-fragments: rra[tile][kt2][mt2][lane][8]
__global__ void prep_rra(const float* __restrict__ rel_rec, __bf16* __restrict__ rra) {
  int id = blockIdx.x * 256 + threadIdx.x;  // 54*256 = 13824
  int tile = id / 768, r = id % 768;
  int kt2 = r / 192, r2 = r % 192, mt2 = r2 >> 6, l = r2 & 63;
  int ebase = tile * 128 + kt2 * 32 + (l >> 4) * 8;
  int n = mt2 * 16 + (l & 15);
  bf16x8 v;
#pragma unroll
  for (int j = 0; j < 8; ++j) {
    int e = ebase + j;
    v[j] = (__bf16)((e < Ee) ? rel_rec[(size_t)e * Nn + n] : 0.f);
  }
  ((bf16x8*)rra)[id] = v;
}

// transpose node-side weights (fp32) for coalesced lane reads
__global__ void prep_node(const float* __restrict__ at5_w1, const float* __restrict__ at5_w2,
                          const float* __restrict__ o1_w, const float* __restrict__ o2_w,
                          const float* __restrict__ o3_w, float* __restrict__ ws) {
  int id = blockIdx.x * 256 + threadIdx.x;
  float* T1 = ws;
  float* T2 = T1 + 67600;
  float* To1 = T2 + 67600;
  float* To2 = To1 + 66560;
  float* To3 = To2 + 65536;
  if (id < 67600) { int o = id % 260, k = id / 260; T1[k * 260 + o] = at5_w1[o * 260 + k]; return; }
  id -= 67600;
  if (id < 67600) { int o = id % 260, k = id / 260; T2[k * 260 + o] = at5_w2[o * 260 + k]; return; }
  id -= 67600;
  if (id < 66560) { int o = id & 255, k = id >> 8; To1[k * 256 + o] = o1_w[o * 260 + k]; return; }
  id -= 66560;
  if (id < 65536) { int o = id & 255, k = id >> 8; To2[k * 256 + o] = o2_w[o * 256 + k]; return; }
  id -= 65536;
  if (id < 1024) { int f = id & 3, k = id >> 2; To3[k * 4 + f] = o3_w[f * 256 + k]; }
}

__global__ __launch_bounds__(256, 4)
void node_kernel(const float* __restrict__ part, int NT, const float* __restrict__ x,
                 const float* __restrict__ T1, const float* __restrict__ T2,
                 const float* __restrict__ To1, const float* __restrict__ To2,
                 const float* __restrict__ To3, const float* __restrict__ at5_b1,
                 const float* __restrict__ at5_b2, const float* __restrict__ at5_g,
                 const float* __restrict__ at5_be, const float* __restrict__ o1_b,
                 const float* __restrict__ o2_b, const float* __restrict__ o3_b,
                 float* __restrict__ out) {
  __shared__ float bufA[12 * 264], bufB[12 * 264], xres[12 * 4];
  const int tid = threadIdx.x;
  const int slice = blockIdx.x >> 2, rg = blockIdx.x & 3;
  const int n0 = rg * 12;
  for (int t = tid; t < 12 * 256; t += 256) {
    int r = t >> 8, h = t & 255;
    float s = 0.f;
    for (int tt = 0; tt < NT; ++tt)
      s += part[(((size_t)slice * NT + tt) * Nn + n0 + r) * Hh + h];
    bufA[r * 264 + h] = s;
  }
  if (tid < 48) {
    int r = tid >> 2, f = tid & 3;
    float v = x[(size_t)slice * 192 + (n0 + r) * 4 + f];
    bufA[r * 264 + 256 + f] = v;
    xres[tid] = v;
  }
  __syncthreads();

  auto layer = [&](const float* WT, const float* bsrc, const float* in, float* outb,
                   int K, int O, int act, const float* gsc, const float* gbe) {
    for (int o = tid; o < O; o += 256) {
      float a[12];
      float bb = bsrc[o];
#pragma unroll
      for (int r = 0; r < 12; ++r) a[r] = bb;
      for (int k = 0; k < K; ++k) {
        float w = WT[k * O + o];
#pragma unroll
        for (int r = 0; r < 12; ++r) a[r] = fmaf(in[r * 264 + k], w, a[r]);
      }
      float scv = 1.f, bev = 0.f;
      if (act == 2) { scv = gsc[o] * BN_RS; bev = gbe[o]; }
#pragma unroll
      for (int r = 0; r < 12; ++r) {
        float v = a[r];
        v = (act == 0) ? fmaxf(v, 0.f) : eluf(v);
        if (act == 2) v = v * scv + bev;
        outb[r * 264 + o] = v;
      }
    }
    __syncthreads();
  };

  layer(T1, at5_b1, bufA, bufB, 260, 260, 1, nullptr, nullptr);
  layer(T2, at5_b2, bufB, bufA, 260, 260, 2, at5_g, at5_be);
  layer(To1, o1_b, bufA, bufB, 260, 256, 0, nullptr, nullptr);
  layer(To2, o2_b, bufB, bufA, 256, 256, 0, nullptr, nullptr);
  if (tid < 48) {
    int r = tid >> 2, f = tid & 3;
    float s = o3_b[f];
    for (int k = 0; k < 256; ++k) s = fmaf(bufA[r * 264 + k], To3[k * 4 + f], s);
    out[(size_t)slice * 192 + (n0 + r) * 4 + f] = xres[tid] + s;
  }
}

extern "C" void kernel_launch(void* const* d_in, const int* in_sizes, int n_in,
                              void* d_out, int out_size, void* d_ws, size_t ws_size,
                              hipStream_t stream) {
  const float* x = (const float*)d_in[0];
  const float* rel_rec = (const float*)d_in[1];
  const float* rel_send = (const float*)d_in[2];
  const float* rel_type = (const float*)d_in[3];
  const float* mf1_w = (const float*)d_in[4];
  const float* mf1_b = (const float*)d_in[5];
  const float* mf2_w = (const float*)d_in[6];
  const float* mf2_b = (const float*)d_in[7];
  const float* at1_w1 = (const float*)d_in[8];
  const float* at1_b1 = (const float*)d_in[9];
  const float* at1_w2 = (const float*)d_in[10];
  const float* at1_b2 = (const float*)d_in[11];
  const float* at1_g = (const float*)d_in[12];
  const float* at1_be = (const float*)d_in[13];
  const float* at5_w1 = (const float*)d_in[14];
  const float* at5_b1 = (const float*)d_in[15];
  const float* at5_w2 = (const float*)d_in[16];
  const float* at5_b2 = (const float*)d_in[17];
  const float* at5_g = (const float*)d_in[18];
  const float* at5_be = (const float*)d_in[19];
  const float* o1_w = (const float*)d_in[20];
  const float* o1_b = (const float*)d_in[21];
  const float* o2_w = (const float*)d_in[22];
  const float* o2_b = (const float*)d_in[23];
  const float* o3_w = (const float*)d_in[24];
  const float* o3_b = (const float*)d_in[25];

  char* ws = (char*)d_ws;
  __bf16* wf = (__bf16*)(ws + WS_WF);
  __bf16* rra = (__bf16*)(ws + WS_RRA);
  float* tnode = (float*)(ws + WS_TN);
  float* agg = (float*)(ws + WS_AGG);

  const bool partial = ws_size >= WS_NEED_PART;

  prep_frag<<<128, 256, 0, stream>>>(mf2_w, at1_w1, at1_w2, wf);
  prep_rra<<<54, 256, 0, stream>>>(rel_rec, rra);
  prep_node<<<1049, 256, 0, stream>>>(at5_w1, at5_w2, o1_w, o2_w, o3_w, tnode);

  if (partial) {
    hipFuncSetAttribute((const void*)edge_kernel<true>,
                        hipFuncAttributeMaxDynamicSharedMemorySize, LDS_EDGE_BYTES);
    edge_kernel<true><<<BT * NTILES, 512, LDS_EDGE_BYTES, stream>>>(
        x, rel_rec, rel_send, rel_type, mf1_w, mf1_b, mf2_b, at1_b1, at1_b2,
        at1_g, at1_be, wf, rra, agg);
    node_kernel<<<256, 256, 0, stream>>>(agg, NTILES, x, tnode, tnode + 67600,
                                         tnode + 135200, tnode + 201760, tnode + 267296,
                                         at5_b1, at5_b2, at5_g, at5_be,
                                         o1_b, o2_b, o3_b, (float*)d_out);
  } else {
    hipMemsetAsync(agg, 0, (size_t)BT * Nn * Hh * 4, stream);
    hipFuncSetAttribute((const void*)edge_kernel<false>,
                        hipFuncAttributeMaxDynamicSharedMemorySize, LDS_EDGE_BYTES);
    edge_kernel<false><<<BT * NTILES, 512, LDS_EDGE_BYTES, stream>>>(
        x, rel_rec, rel_send, rel_type, mf1_w, mf1_b, mf2_b, at1_b1, at1_b2,
        at1_g, at1_be, wf, rra, agg);
    node_kernel<<<256, 256, 0, stream>>>(agg, 1, x, tnode, tnode + 67600,
                                         tnode + 135200, tnode + 201760, tnode + 267296,
                                         at5_b1, at5_b2, at5_g, at5_be,
                                         o1_b, o2_b, o3_b, (float*)d_out);
  }
}